// Round 13
// baseline (456.738 us; speedup 1.0000x reference)
//
#include <hip/hip_runtime.h>

typedef unsigned short u16;
typedef unsigned int   u32;

#define HID   128
#define HEADS 4
#define CH    128
#define HC    512
#define UT    32   // nodes per block in the update GEMM

typedef __bf16 bf16x8v __attribute__((ext_vector_type(8)));
typedef float  f32x4v  __attribute__((ext_vector_type(4)));
union FragU { uint4 u; bf16x8v b; };

// bf16 pack/unpack for INTERNAL workspace tensors only (inputs/outputs f32)
static __device__ __forceinline__ float bf2f(u16 u) {
  union { u32 u; float f; } x;
  x.u = ((u32)u) << 16;
  return x.f;
}
static __device__ __forceinline__ u16 f2bf(float f) {
  union { float f; u32 u; } x;
  x.f = f;
  u32 r = x.u + 0x7fffu + ((x.u >> 16) & 1u);
  return (u16)(r >> 16);
}

static __device__ __forceinline__ void unpack8(uint4 raw, float* dst) {
  dst[0] = bf2f((u16)(raw.x & 0xffffu));
  dst[1] = bf2f((u16)(raw.x >> 16));
  dst[2] = bf2f((u16)(raw.y & 0xffffu));
  dst[3] = bf2f((u16)(raw.y >> 16));
  dst[4] = bf2f((u16)(raw.z & 0xffffu));
  dst[5] = bf2f((u16)(raw.z >> 16));
  dst[6] = bf2f((u16)(raw.w & 0xffffu));
  dst[7] = bf2f((u16)(raw.w >> 16));
}

// process one pair of edges: dot + online softmax + v-accumulate
static __device__ __forceinline__ void attn_pair(uint4 k0, uint4 k1, uint4 v0,
                                                 uint4 v1, const float* qf,
                                                 float& m, float& l,
                                                 float* acc) {
  const float sscale = 0.08838834764831845f;  // 1/sqrt(128)
  float k0f[8], k1f[8];
  unpack8(k0, k0f);
  unpack8(k1, k1f);
  float p0 = 0.f, p1 = 0.f;
  for (int j = 0; j < 8; ++j) {
    p0 = fmaf(k0f[j], qf[j], p0);
    p1 = fmaf(k1f[j], qf[j], p1);
  }
  p0 += __shfl_xor(p0, 1);
  p1 += __shfl_xor(p1, 1);
  p0 += __shfl_xor(p0, 2);
  p1 += __shfl_xor(p1, 2);
  p0 += __shfl_xor(p0, 4);
  p1 += __shfl_xor(p1, 4);
  p0 += __shfl_xor(p0, 8);
  p1 += __shfl_xor(p1, 8);
  float sc0 = p0 * sscale;
  float sc1 = p1 * sscale;
  float mnew = fmaxf(m, fmaxf(sc0, sc1));
  float so = __expf(m - mnew);
  float pe0 = __expf(sc0 - mnew);
  float pe1 = __expf(sc1 - mnew);
  l = l * so + pe0 + pe1;
  float v0f[8], v1f[8];
  unpack8(v0, v0f);
  unpack8(v1, v1f);
  for (int j = 0; j < 8; ++j)
    acc[j] = fmaf(acc[j], so, fmaf(pe0, v0f[j], pe1 * v1f[j]));
  m = mnew;
}

// ---------------- zero int buffer ----------------
__global__ void zero_kernel(int* p, int n) {
  int i = blockIdx.x * 256 + threadIdx.x;
  if (i < n) p[i] = 0;
}

// ---------------- CSR: histogram ----------------
__global__ void hist_kernel(const int* dst_idx, int* deg, int E) {
  int e = blockIdx.x * 256 + threadIdx.x;
  if (e < E) atomicAdd(&deg[dst_idx[e]], 1);
}

// ---------------- CSR scan phase 1: per-block sums ----------------
__global__ void blocksum_kernel(const int* deg, int* bsums, int n) {
  __shared__ int buf[256];
  int i = blockIdx.x * 256 + threadIdx.x;
  int v = 0;
  if (i < n) v = deg[i];
  buf[threadIdx.x] = v;
  __syncthreads();
  for (int off = 128; off > 0; off >>= 1) {
    if (threadIdx.x < off) buf[threadIdx.x] += buf[threadIdx.x + off];
    __syncthreads();
  }
  if (threadIdx.x == 0) bsums[blockIdx.x] = buf[0];
}

// ---------------- CSR scan phase 2: exclusive scan of block sums ------------
__global__ void scanb_kernel(const int* bsums, int* boffs, int nb) {
  __shared__ int buf[256];
  __shared__ int carry_s;
  int tid = threadIdx.x;
  if (tid == 0) carry_s = 0;
  __syncthreads();
  for (int base = 0; base < nb; base += 256) {
    int i = base + tid;
    int v = 0;
    if (i < nb) v = bsums[i];
    buf[tid] = v;
    __syncthreads();
    for (int off = 1; off < 256; off <<= 1) {
      int t = 0;
      if (tid >= off) t = buf[tid - off];
      __syncthreads();
      buf[tid] += t;
      __syncthreads();
    }
    int incl = buf[tid] + carry_s;
    if (i < nb) boffs[i] = incl - v;
    __syncthreads();
    if (tid == 255) carry_s = incl;
    __syncthreads();
  }
}

// ---------------- CSR scan phase 3: in-block scan + block offset ------------
__global__ void scanfinal_kernel(const int* deg, const int* boffs,
                                 int* row_ptr, int* cursor, int n) {
  __shared__ int buf[256];
  int tid = threadIdx.x;
  int i = blockIdx.x * 256 + tid;
  int v = 0;
  if (i < n) v = deg[i];
  buf[tid] = v;
  __syncthreads();
  for (int off = 1; off < 256; off <<= 1) {
    int t = 0;
    if (tid >= off) t = buf[tid - off];
    __syncthreads();
    buf[tid] += t;
    __syncthreads();
  }
  int incl = buf[tid] + boffs[blockIdx.x];
  if (i < n) {
    row_ptr[i + 1] = incl;
    cursor[i] = incl - v;
  }
  if (i == 0) row_ptr[0] = 0;
}

// ---------------- CSR: scatter ----------------
__global__ void scatter_kernel(const int* src_idx, const int* dst_idx,
                               int* cursor, int* col, int E) {
  int e = blockIdx.x * 256 + threadIdx.x;
  if (e < E) {
    int pos = atomicAdd(&cursor[dst_idx[e]], 1);
    col[pos] = src_idx[e];
  }
}

// ---- pack h_X into MFMA A-fragment order (bf16) ----
__global__ void packH_kernel(const float* __restrict__ hX,
                             u16* __restrict__ hpack, int N, int total) {
  int i = blockIdx.x * 256 + threadIdx.x;
  if (i >= total) return;
  int j = i & 7;
  int lane = (i >> 3) & 63;
  int kc = (i >> 9) & 3;
  int ntile = i >> 11;
  int node = ntile * 16 + (lane & 15);
  int k = kc * 32 + (lane >> 4) * 8 + j;
  float v = (node < N) ? hX[(size_t)node * HID + k] : 0.f;
  hpack[i] = f2bf(v);
}

// ---- pack [Wq|Wk|Wv|Wskip] (1664 cols) into B-fragment order (bf16) ----
__global__ void packW4_kernel(const float* __restrict__ Wq,
                              const float* __restrict__ Wk,
                              const float* __restrict__ Wv,
                              const float* __restrict__ Wsk,
                              u16* __restrict__ Wp, int total) {
  int i = blockIdx.x * 256 + threadIdx.x;
  if (i >= total) return;
  int j = i & 7;
  int lane = (i >> 3) & 63;
  int kc = (i >> 9) & 3;
  int ct = i >> 11;
  int n = ct * 16 + (lane & 15);
  int k = kc * 32 + (lane >> 4) * 8 + j;
  float w;
  if (n < 512) w = Wq[(size_t)k * HC + n];
  else if (n < 1024) w = Wk[(size_t)k * HC + (n - 512)];
  else if (n < 1536) w = Wv[(size_t)k * HC + (n - 1024)];
  else w = Wsk[(size_t)k * HID + (n - 1536)];
  Wp[i] = f2bf(w);
}

// ---- single MFMA projection: q|k|v|skip in one launch ----
// C[64 nodes x 64 cols] per block, 4 waves; wave wv owns col-tile
// ct = blockIdx.y*4+wv (0..103). Epilogue routes by column segment.
__global__ __launch_bounds__(256) void mfma_proj_kernel(
    const u16* __restrict__ hpack, const u16* __restrict__ Wp,
    const float* __restrict__ bq, const float* __restrict__ bk,
    const float* __restrict__ bv, const float* __restrict__ bsk,
    u16* __restrict__ qb, u16* __restrict__ kbuf, u16* __restrict__ vbuf,
    float* __restrict__ skipf, int N) {
  int t = threadIdx.x;
  int wv = t >> 6;
  int L = t & 63;
  int ct = blockIdx.y * 4 + wv;
  int nt0 = blockIdx.x * 4;

  f32x4v acc[4];
  for (int mt = 0; mt < 4; ++mt) acc[mt] = (f32x4v){0.f, 0.f, 0.f, 0.f};

  const u16* wb = Wp + (size_t)ct * 2048;
  const u16* hb = hpack + (size_t)nt0 * 2048;

  for (int kc = 0; kc < 4; ++kc) {
    FragU bf;
    bf.u = *(const uint4*)(wb + kc * 512 + L * 8);
    for (int mt = 0; mt < 4; ++mt) {
      FragU af;
      af.u = *(const uint4*)(hb + mt * 2048 + kc * 512 + L * 8);
      acc[mt] =
          __builtin_amdgcn_mfma_f32_16x16x32_bf16(af.b, bf.b, acc[mt], 0, 0, 0);
    }
  }

  // C/D layout: col = lane&15, row = (lane>>4)*4 + reg
  int colq = L & 15;
  int quad = L >> 4;
  int n = ct * 16 + colq;
  // per-wave-uniform segment routing (16-col tiles never straddle segments)
  u16* outB;
  const float* bias;
  int nl;
  int isF32 = 0;
  if (n < 512) {
    outB = qb; bias = bq; nl = n;
  } else if (n < 1024) {
    outB = kbuf; bias = bk; nl = n - 512;
  } else if (n < 1536) {
    outB = vbuf; bias = bv; nl = n - 1024;
  } else {
    outB = (u16*)skipf; bias = bsk; nl = n - 1536; isF32 = 1;
  }
  float bval = bias[nl];
  for (int mt = 0; mt < 4; ++mt) {
    for (int rg = 0; rg < 4; ++rg) {
      int node = (nt0 + mt) * 16 + quad * 4 + rg;
      if (node < N) {
        float val = acc[mt][rg] + bval;
        if (isF32) {
          skipf[(size_t)node * HID + nl] = val;
        } else {
          outB[(size_t)node * HC + nl] = f2bf(val);
        }
      }
    }
  }
}

// ---- FUSED per-node attention, software-pipelined (prefetch next pair) ----
// One wave per dst node; 8 gathers in flight across 2 pipelined pairs.
// __launch_bounds__(256,8) pins VGPR<=64 so occupancy stays 8 waves/SIMD.
__global__ __launch_bounds__(256, 8) void fused_attn_kernel(
    const u16* __restrict__ qb, const u16* __restrict__ kb,
    const u16* __restrict__ vb, const int* __restrict__ row_ptr,
    const int* __restrict__ col_src, float* out, int N) {
  int node = blockIdx.x * 4 + (threadIdx.x >> 6);
  if (node >= N) return;
  int lane = threadIdx.x & 63;
  int head = lane >> 4;
  int r = lane & 15;
  int foff = head * CH + r * 8;

  float qf[8];
  unpack8(*(const uint4*)(qb + (size_t)node * HC + foff), qf);

  float m = -3.402823466e38f;
  float l = 0.f;
  float acc[8];
  for (int j = 0; j < 8; ++j) acc[j] = 0.f;

  int e0 = row_ptr[node];
  int e1 = row_ptr[node + 1];
  int e = e0;

  uint4 ka, kc_, va, vc_;
  if (e + 2 <= e1) {  // prologue: load first pair
    int s0 = col_src[e];
    int s1 = col_src[e + 1];
    ka = *(const uint4*)(kb + (size_t)s0 * HC + foff);
    kc_ = *(const uint4*)(kb + (size_t)s1 * HC + foff);
    va = *(const uint4*)(vb + (size_t)s0 * HC + foff);
    vc_ = *(const uint4*)(vb + (size_t)s1 * HC + foff);
  }
  for (; e + 4 <= e1; e += 2) {
    // prefetch pair (e+2, e+3) before processing current pair
    int s2 = col_src[e + 2];
    int s3 = col_src[e + 3];
    uint4 nk0 = *(const uint4*)(kb + (size_t)s2 * HC + foff);
    uint4 nk1 = *(const uint4*)(kb + (size_t)s3 * HC + foff);
    uint4 nv0 = *(const uint4*)(vb + (size_t)s2 * HC + foff);
    uint4 nv1 = *(const uint4*)(vb + (size_t)s3 * HC + foff);
    attn_pair(ka, kc_, va, vc_, qf, m, l, acc);
    ka = nk0;
    kc_ = nk1;
    va = nv0;
    vc_ = nv1;
  }
  if (e + 2 <= e1) {  // drain pipelined pair
    attn_pair(ka, kc_, va, vc_, qf, m, l, acc);
    e += 2;
  }
  if (e < e1) {  // single-edge tail
    const float sscale = 0.08838834764831845f;
    int s0 = col_src[e];
    uint4 k0 = *(const uint4*)(kb + (size_t)s0 * HC + foff);
    uint4 v0 = *(const uint4*)(vb + (size_t)s0 * HC + foff);
    float k0f[8];
    unpack8(k0, k0f);
    float p0 = 0.f;
    for (int j = 0; j < 8; ++j) p0 = fmaf(k0f[j], qf[j], p0);
    p0 += __shfl_xor(p0, 1);
    p0 += __shfl_xor(p0, 2);
    p0 += __shfl_xor(p0, 4);
    p0 += __shfl_xor(p0, 8);
    float sc0 = p0 * sscale;
    float mnew = fmaxf(m, sc0);
    float so = __expf(m - mnew);
    float pe0 = __expf(sc0 - mnew);
    l = l * so + pe0;
    float v0f[8];
    unpack8(v0, v0f);
    for (int j = 0; j < 8; ++j) acc[j] = fmaf(acc[j], so, pe0 * v0f[j]);
    m = mnew;
  }

  float inv = 0.f;
  if (l > 0.f) inv = 1.0f / l;
  float val[8];
  for (int j = 0; j < 8; ++j) {
    float x = acc[j] * inv;
    x += __shfl_xor(x, 16);
    x += __shfl_xor(x, 32);
    val[j] = x * 0.25f;  // mean over 4 heads
  }

  if (head == 0) {
    float* p = out + (size_t)node * HID + r * 8;
    float4 a = *(const float4*)(p);
    float4 b = *(const float4*)(p + 4);
    a.x += val[0]; a.y += val[1]; a.z += val[2]; a.w += val[3];
    b.x += val[4]; b.y += val[5]; b.z += val[6]; b.w += val[7];
    *(float4*)(p) = a;
    *(float4*)(p + 4) = b;
  }
}

// ---------------- cvec = h_t @ Wup[128:256] + bup (all f32) ----------------
__global__ void cvec_kernel(const float* h_t, const float* Wup,
                            const float* bup, float* cvec) {
  int c = threadIdx.x;
  float acc = bup[c];
  for (int k = 0; k < 128; ++k)
    acc = fmaf(h_t[k], Wup[(size_t)(128 + k) * 128 + c], acc);
  cvec[c] = acc;
}

// ------- update GEMM + relu + LayerNorm, in-place on d_out (f32) -------
__global__ __launch_bounds__(256) void ATTLayer_19396072308956_kernel(
    float* out, const float* __restrict__ Wup, const float* __restrict__ cvec,
    const float* __restrict__ gamma, const float* __restrict__ beta, int N) {
  __shared__ float Wl[64 * 128];
  __shared__ float Hl[UT * 128];
  int t = threadIdx.x;
  int n0 = blockIdx.x * UT;

  for (int i = t * 4; i < UT * 128; i += 1024) {
    int node = n0 + (i >> 7);
    float4 v;
    if (node < N) {
      v = *(const float4*)(out + (size_t)node * HID + (i & 127));
    } else {
      v.x = 0.f; v.y = 0.f; v.z = 0.f; v.w = 0.f;
    }
    *(float4*)(Hl + i) = v;
  }

  int wv = t >> 6;
  int r = t & 63;
  int c0 = 2 * r;
  float2 cv = *(const float2*)(cvec + c0);
  float a0[8];
  float a1[8];
  for (int j = 0; j < 8; ++j) {
    a0[j] = cv.x;
    a1[j] = cv.y;
  }

  for (int ph = 0; ph < 2; ++ph) {
    __syncthreads();
    for (int i = t * 4; i < 64 * 128; i += 1024) {
      *(float4*)(Wl + i) = *(const float4*)(Wup + (size_t)ph * 64 * 128 + i);
    }
    __syncthreads();
    const float* hbase = Hl + (wv * 8) * 128 + ph * 64;
#pragma unroll 8
    for (int k = 0; k < 64; ++k) {
      float2 w2 = *(const float2*)(Wl + k * 128 + c0);
      for (int j = 0; j < 8; ++j) {
        float h = hbase[j * 128 + k];
        a0[j] = fmaf(h, w2.x, a0[j]);
        a1[j] = fmaf(h, w2.y, a1[j]);
      }
    }
  }

  float2 g = *(const float2*)(gamma + c0);
  float2 b = *(const float2*)(beta + c0);
  for (int j = 0; j < 8; ++j) {
    int node = n0 + wv * 8 + j;
    float r0 = fmaxf(a0[j], 0.f);
    float r1 = fmaxf(a1[j], 0.f);
    float s = r0 + r1;
    for (int msk = 1; msk < 64; msk <<= 1) s += __shfl_xor(s, msk);
    float mean = s * (1.0f / 128.0f);
    float d0 = r0 - mean;
    float d1 = r1 - mean;
    float sq = d0 * d0 + d1 * d1;
    for (int msk = 1; msk < 64; msk <<= 1) sq += __shfl_xor(sq, msk);
    float rstd = rsqrtf(sq * (1.0f / 128.0f) + 1e-5f);
    if (node < N) {
      float2 o;
      o.x = d0 * rstd * g.x + b.x;
      o.y = d1 * rstd * g.y + b.y;
      *(float2*)(out + (size_t)node * HID + c0) = o;
    }
  }
}

extern "C" void kernel_launch(void* const* d_in, const int* in_sizes, int n_in,
                              void* d_out, int out_size, void* d_ws,
                              size_t ws_size, hipStream_t stream) {
  (void)n_in;
  (void)out_size;
  (void)ws_size;

  const int* edge_index = (const int*)d_in[0];
  const float* hX    = (const float*)d_in[1];
  const float* h_t   = (const float*)d_in[2];
  const float* Wq    = (const float*)d_in[3];
  const float* bq    = (const float*)d_in[4];
  const float* Wk    = (const float*)d_in[5];
  const float* bk    = (const float*)d_in[6];
  const float* Wv    = (const float*)d_in[7];
  const float* bv    = (const float*)d_in[8];
  const float* Wskip = (const float*)d_in[9];
  const float* bskip = (const float*)d_in[10];
  const float* Wup   = (const float*)d_in[11];
  const float* bup   = (const float*)d_in[12];
  const float* gamma = (const float*)d_in[13];
  const float* beta  = (const float*)d_in[14];

  const int E = in_sizes[0] / 2;
  const int N = in_sizes[1] / HID;
  const int* src_idx = edge_index;
  const int* dst_idx = edge_index + E;
  const int NB = (N + 255) / 256;
  const int NTILES = (N + 15) / 16;
  const int NTILES4 = ((NTILES + 3) / 4) * 4;

  // ---- workspace layout (~170 MB peak, proven fits in round 12) ----
  char* w = (char*)d_ws;
  size_t off = 0;
  float* cvec = (float*)(w + off);
  off += 256 * 4;
  int* deg = (int*)(w + off);
  off += ((size_t)N * 4 + 255) / 256 * 256;
  int* row_ptr = (int*)(w + off);
  off += ((size_t)(N + 1) * 4 + 255) / 256 * 256;
  int* cursor = (int*)(w + off);
  off += ((size_t)N * 4 + 255) / 256 * 256;
  int* bsums = (int*)(w + off);
  off += ((size_t)NB * 4 + 255) / 256 * 256;
  int* boffs = (int*)(w + off);
  off += ((size_t)NB * 4 + 255) / 256 * 256;
  int* col = (int*)(w + off);
  off += ((size_t)E * 4 + 255) / 256 * 256;
  u16* hpack = (u16*)(w + off);
  off += ((size_t)NTILES4 * 2048 * 2 + 255) / 256 * 256;
  u16* Wp = (u16*)(w + off);     // [Wq|Wk|Wv|Wskip] 1664 cols, B-frag order
  off += ((size_t)128 * 1664 * 2 + 255) / 256 * 256;
  u16* bigA = (u16*)(w + off);   // q
  off += ((size_t)N * HC * 2 + 255) / 256 * 256;
  u16* bigB = (u16*)(w + off);   // k
  off += ((size_t)N * HC * 2 + 255) / 256 * 256;
  u16* bigC = (u16*)(w + off);   // v
  off += ((size_t)N * HC * 2 + 255) / 256 * 256;

  float* out = (float*)d_out;

  // ---- CSR build (parallel 3-phase scan) ----
  zero_kernel<<<NB, 256, 0, stream>>>(deg, N);
  hist_kernel<<<(E + 255) / 256, 256, 0, stream>>>(dst_idx, deg, E);
  blocksum_kernel<<<NB, 256, 0, stream>>>(deg, bsums, N);
  scanb_kernel<<<1, 256, 0, stream>>>(bsums, boffs, NB);
  scanfinal_kernel<<<NB, 256, 0, stream>>>(deg, boffs, row_ptr, cursor, N);
  scatter_kernel<<<(E + 255) / 256, 256, 0, stream>>>(src_idx, dst_idx, cursor,
                                                      col, E);

  // ---- packing for MFMA ----
  int totH = NTILES4 * 2048;
  packH_kernel<<<(totH + 255) / 256, 256, 0, stream>>>(hX, hpack, N, totH);
  packW4_kernel<<<(128 * 1664 + 255) / 256, 256, 0, stream>>>(
      Wq, Wk, Wv, Wskip, Wp, 128 * 1664);

  // ---- cvec ----
  cvec_kernel<<<1, 128, 0, stream>>>(h_t, Wup, bup, cvec);

  // ---- single MFMA projection: q->bigA, k->bigB, v->bigC, skip->d_out ----
  mfma_proj_kernel<<<dim3(NTILES4 / 4, 26), 256, 0, stream>>>(
      hpack, Wp, bq, bk, bv, bskip, bigA, bigB, bigC, out, N);

  // ---- fused score + online softmax + aggregate (pipelined gathers) ----
  fused_attn_kernel<<<(N + 3) / 4, 256, 0, stream>>>(bigA, bigB, bigC, row_ptr,
                                                     col, out, N);

  // ---- update GEMM + relu + LayerNorm, in-place on d_out (tiled) ----
  ATTLayer_19396072308956_kernel<<<(N + UT - 1) / UT, 256, 0, stream>>>(
      out, Wup, cvec, gamma, beta, N);
}

// Round 14
// 430.951 us; speedup vs baseline: 1.0598x; 1.0598x over previous
//
#include <hip/hip_runtime.h>

typedef unsigned short u16;
typedef unsigned int   u32;

#define HID   128
#define HEADS 4
#define CH    128
#define HC    512
#define UT    32   // nodes per block in the update GEMM

typedef __bf16 bf16x8v __attribute__((ext_vector_type(8)));
typedef float  f32x4v  __attribute__((ext_vector_type(4)));
union FragU { uint4 u; bf16x8v b; };

// bf16 pack/unpack for INTERNAL workspace tensors only (inputs/outputs f32)
static __device__ __forceinline__ float bf2f(u16 u) {
  union { u32 u; float f; } x;
  x.u = ((u32)u) << 16;
  return x.f;
}
static __device__ __forceinline__ u16 f2bf(float f) {
  union { float f; u32 u; } x;
  x.f = f;
  u32 r = x.u + 0x7fffu + ((x.u >> 16) & 1u);
  return (u16)(r >> 16);
}

static __device__ __forceinline__ void unpack8(uint4 raw, float* dst) {
  dst[0] = bf2f((u16)(raw.x & 0xffffu));
  dst[1] = bf2f((u16)(raw.x >> 16));
  dst[2] = bf2f((u16)(raw.y & 0xffffu));
  dst[3] = bf2f((u16)(raw.y >> 16));
  dst[4] = bf2f((u16)(raw.z & 0xffffu));
  dst[5] = bf2f((u16)(raw.z >> 16));
  dst[6] = bf2f((u16)(raw.w & 0xffffu));
  dst[7] = bf2f((u16)(raw.w >> 16));
}

// ---------------- zero int buffer ----------------
__global__ void zero_kernel(int* p, int n) {
  int i = blockIdx.x * 256 + threadIdx.x;
  if (i < n) p[i] = 0;
}

// ---------------- CSR: histogram ----------------
__global__ void hist_kernel(const int* dst_idx, int* deg, int E) {
  int e = blockIdx.x * 256 + threadIdx.x;
  if (e < E) atomicAdd(&deg[dst_idx[e]], 1);
}

// ---------------- CSR scan phase 1: per-block sums ----------------
__global__ void blocksum_kernel(const int* deg, int* bsums, int n) {
  __shared__ int buf[256];
  int i = blockIdx.x * 256 + threadIdx.x;
  int v = 0;
  if (i < n) v = deg[i];
  buf[threadIdx.x] = v;
  __syncthreads();
  for (int off = 128; off > 0; off >>= 1) {
    if (threadIdx.x < off) buf[threadIdx.x] += buf[threadIdx.x + off];
    __syncthreads();
  }
  if (threadIdx.x == 0) bsums[blockIdx.x] = buf[0];
}

// ---------------- CSR scan phase 2: exclusive scan of block sums ------------
__global__ void scanb_kernel(const int* bsums, int* boffs, int nb) {
  __shared__ int buf[256];
  __shared__ int carry_s;
  int tid = threadIdx.x;
  if (tid == 0) carry_s = 0;
  __syncthreads();
  for (int base = 0; base < nb; base += 256) {
    int i = base + tid;
    int v = 0;
    if (i < nb) v = bsums[i];
    buf[tid] = v;
    __syncthreads();
    for (int off = 1; off < 256; off <<= 1) {
      int t = 0;
      if (tid >= off) t = buf[tid - off];
      __syncthreads();
      buf[tid] += t;
      __syncthreads();
    }
    int incl = buf[tid] + carry_s;
    if (i < nb) boffs[i] = incl - v;
    __syncthreads();
    if (tid == 255) carry_s = incl;
    __syncthreads();
  }
}

// ---------------- CSR scan phase 3: in-block scan + block offset ------------
__global__ void scanfinal_kernel(const int* deg, const int* boffs,
                                 int* row_ptr, int* cursor, int n) {
  __shared__ int buf[256];
  int tid = threadIdx.x;
  int i = blockIdx.x * 256 + tid;
  int v = 0;
  if (i < n) v = deg[i];
  buf[tid] = v;
  __syncthreads();
  for (int off = 1; off < 256; off <<= 1) {
    int t = 0;
    if (tid >= off) t = buf[tid - off];
    __syncthreads();
    buf[tid] += t;
    __syncthreads();
  }
  int incl = buf[tid] + boffs[blockIdx.x];
  if (i < n) {
    row_ptr[i + 1] = incl;
    cursor[i] = incl - v;
  }
  if (i == 0) row_ptr[0] = 0;
}

// ---------------- CSR: scatter ----------------
__global__ void scatter_kernel(const int* src_idx, const int* dst_idx,
                               int* cursor, int* col, int E) {
  int e = blockIdx.x * 256 + threadIdx.x;
  if (e < E) {
    int pos = atomicAdd(&cursor[dst_idx[e]], 1);
    col[pos] = src_idx[e];
  }
}

// ---- pack h_X into MFMA A-fragment order (bf16) ----
__global__ void packH_kernel(const float* __restrict__ hX,
                             u16* __restrict__ hpack, int N, int total) {
  int i = blockIdx.x * 256 + threadIdx.x;
  if (i >= total) return;
  int j = i & 7;
  int lane = (i >> 3) & 63;
  int kc = (i >> 9) & 3;
  int ntile = i >> 11;
  int node = ntile * 16 + (lane & 15);
  int k = kc * 32 + (lane >> 4) * 8 + j;
  float v = (node < N) ? hX[(size_t)node * HID + k] : 0.f;
  hpack[i] = f2bf(v);
}

// ---- pack [Wq|Wk|Wv|Wskip] (1664 cols) into B-fragment order (bf16) ----
__global__ void packW4_kernel(const float* __restrict__ Wq,
                              const float* __restrict__ Wk,
                              const float* __restrict__ Wv,
                              const float* __restrict__ Wsk,
                              u16* __restrict__ Wp, int total) {
  int i = blockIdx.x * 256 + threadIdx.x;
  if (i >= total) return;
  int j = i & 7;
  int lane = (i >> 3) & 63;
  int kc = (i >> 9) & 3;
  int ct = i >> 11;
  int n = ct * 16 + (lane & 15);
  int k = kc * 32 + (lane >> 4) * 8 + j;
  float w;
  if (n < 512) w = Wq[(size_t)k * HC + n];
  else if (n < 1024) w = Wk[(size_t)k * HC + (n - 512)];
  else if (n < 1536) w = Wv[(size_t)k * HC + (n - 1024)];
  else w = Wsk[(size_t)k * HID + (n - 1536)];
  Wp[i] = f2bf(w);
}

// ---- single MFMA projection: q|k|v|skip in one launch ----
__global__ __launch_bounds__(256) void mfma_proj_kernel(
    const u16* __restrict__ hpack, const u16* __restrict__ Wp,
    const float* __restrict__ bq, const float* __restrict__ bk,
    const float* __restrict__ bv, const float* __restrict__ bsk,
    u16* __restrict__ qb, u16* __restrict__ kbuf, u16* __restrict__ vbuf,
    float* __restrict__ skipf, int N) {
  int t = threadIdx.x;
  int wv = t >> 6;
  int L = t & 63;
  int ct = blockIdx.y * 4 + wv;
  int nt0 = blockIdx.x * 4;

  f32x4v acc[4];
  for (int mt = 0; mt < 4; ++mt) acc[mt] = (f32x4v){0.f, 0.f, 0.f, 0.f};

  const u16* wb = Wp + (size_t)ct * 2048;
  const u16* hb = hpack + (size_t)nt0 * 2048;

  for (int kc = 0; kc < 4; ++kc) {
    FragU bf;
    bf.u = *(const uint4*)(wb + kc * 512 + L * 8);
    for (int mt = 0; mt < 4; ++mt) {
      FragU af;
      af.u = *(const uint4*)(hb + mt * 2048 + kc * 512 + L * 8);
      acc[mt] =
          __builtin_amdgcn_mfma_f32_16x16x32_bf16(af.b, bf.b, acc[mt], 0, 0, 0);
    }
  }

  int colq = L & 15;
  int quad = L >> 4;
  int n = ct * 16 + colq;
  u16* outB;
  const float* bias;
  int nl;
  int isF32 = 0;
  if (n < 512) {
    outB = qb; bias = bq; nl = n;
  } else if (n < 1024) {
    outB = kbuf; bias = bk; nl = n - 512;
  } else if (n < 1536) {
    outB = vbuf; bias = bv; nl = n - 1024;
  } else {
    outB = (u16*)skipf; bias = bsk; nl = n - 1536; isF32 = 1;
  }
  float bval = bias[nl];
  for (int mt = 0; mt < 4; ++mt) {
    for (int rg = 0; rg < 4; ++rg) {
      int node = (nt0 + mt) * 16 + quad * 4 + rg;
      if (node < N) {
        float val = acc[mt][rg] + bval;
        if (isF32) {
          skipf[(size_t)node * HID + nl] = val;
        } else {
          outB[(size_t)node * HC + nl] = f2bf(val);
        }
      }
    }
  }
}

// ---- FUSED per-node attention: 4-edge unroll (8 gathers in flight) ----
// No launch_bounds pin and no cross-iteration prefetch buffers: round-13's
// (256,8) pin at 64 VGPR spilled to scratch (WRITE_SIZE 25->73MB, 127->145us).
// The 4-edge straight-line unroll gets the same 8-deep MLP inside one
// iteration with registers the compiler can retire immediately.
__global__ void fused_attn_kernel(const u16* __restrict__ qb,
                                  const u16* __restrict__ kb,
                                  const u16* __restrict__ vb,
                                  const int* __restrict__ row_ptr,
                                  const int* __restrict__ col_src,
                                  float* out, int N) {
  int node = blockIdx.x * 4 + (threadIdx.x >> 6);
  if (node >= N) return;
  int lane = threadIdx.x & 63;
  int head = lane >> 4;
  int r = lane & 15;
  int foff = head * CH + r * 8;
  const float sscale = 0.08838834764831845f;  // 1/sqrt(128)

  float qf[8];
  unpack8(*(const uint4*)(qb + (size_t)node * HC + foff), qf);

  float m = -3.402823466e38f;
  float l = 0.f;
  float acc[8];
  for (int j = 0; j < 8; ++j) acc[j] = 0.f;

  int e0 = row_ptr[node];
  int e1 = row_ptr[node + 1];
  int e = e0;

  for (; e + 4 <= e1; e += 4) {
    int s0 = col_src[e];
    int s1 = col_src[e + 1];
    int s2 = col_src[e + 2];
    int s3 = col_src[e + 3];
    // issue all 8 gathers before any dependent use
    uint4 k0 = *(const uint4*)(kb + (size_t)s0 * HC + foff);
    uint4 k1 = *(const uint4*)(kb + (size_t)s1 * HC + foff);
    uint4 k2 = *(const uint4*)(kb + (size_t)s2 * HC + foff);
    uint4 k3 = *(const uint4*)(kb + (size_t)s3 * HC + foff);
    uint4 v0 = *(const uint4*)(vb + (size_t)s0 * HC + foff);
    uint4 v1 = *(const uint4*)(vb + (size_t)s1 * HC + foff);
    uint4 v2 = *(const uint4*)(vb + (size_t)s2 * HC + foff);
    uint4 v3 = *(const uint4*)(vb + (size_t)s3 * HC + foff);

    float kf0[8], kf1[8], kf2[8], kf3[8];
    unpack8(k0, kf0);
    unpack8(k1, kf1);
    unpack8(k2, kf2);
    unpack8(k3, kf3);
    float p0 = 0.f, p1 = 0.f, p2 = 0.f, p3 = 0.f;
    for (int j = 0; j < 8; ++j) {
      p0 = fmaf(kf0[j], qf[j], p0);
      p1 = fmaf(kf1[j], qf[j], p1);
      p2 = fmaf(kf2[j], qf[j], p2);
      p3 = fmaf(kf3[j], qf[j], p3);
    }
    p0 += __shfl_xor(p0, 1);
    p1 += __shfl_xor(p1, 1);
    p2 += __shfl_xor(p2, 1);
    p3 += __shfl_xor(p3, 1);
    p0 += __shfl_xor(p0, 2);
    p1 += __shfl_xor(p1, 2);
    p2 += __shfl_xor(p2, 2);
    p3 += __shfl_xor(p3, 2);
    p0 += __shfl_xor(p0, 4);
    p1 += __shfl_xor(p1, 4);
    p2 += __shfl_xor(p2, 4);
    p3 += __shfl_xor(p3, 4);
    p0 += __shfl_xor(p0, 8);
    p1 += __shfl_xor(p1, 8);
    p2 += __shfl_xor(p2, 8);
    p3 += __shfl_xor(p3, 8);
    float sc0 = p0 * sscale;
    float sc1 = p1 * sscale;
    float sc2 = p2 * sscale;
    float sc3 = p3 * sscale;
    float mnew = fmaxf(fmaxf(m, fmaxf(sc0, sc1)), fmaxf(sc2, sc3));
    float so = __expf(m - mnew);
    float pe0 = __expf(sc0 - mnew);
    float pe1 = __expf(sc1 - mnew);
    float pe2 = __expf(sc2 - mnew);
    float pe3 = __expf(sc3 - mnew);
    l = l * so + (pe0 + pe1) + (pe2 + pe3);
    float vf0[8], vf1[8], vf2[8], vf3[8];
    unpack8(v0, vf0);
    unpack8(v1, vf1);
    unpack8(v2, vf2);
    unpack8(v3, vf3);
    for (int j = 0; j < 8; ++j) {
      float add = fmaf(pe0, vf0[j],
                       fmaf(pe1, vf1[j], fmaf(pe2, vf2[j], pe3 * vf3[j])));
      acc[j] = fmaf(acc[j], so, add);
    }
    m = mnew;
  }

  for (; e < e1; ++e) {  // tail: 0-3 edges
    int s0 = col_src[e];
    uint4 k0 = *(const uint4*)(kb + (size_t)s0 * HC + foff);
    uint4 v0 = *(const uint4*)(vb + (size_t)s0 * HC + foff);
    float kf0[8];
    unpack8(k0, kf0);
    float p0 = 0.f;
    for (int j = 0; j < 8; ++j) p0 = fmaf(kf0[j], qf[j], p0);
    p0 += __shfl_xor(p0, 1);
    p0 += __shfl_xor(p0, 2);
    p0 += __shfl_xor(p0, 4);
    p0 += __shfl_xor(p0, 8);
    float sc0 = p0 * sscale;
    float mnew = fmaxf(m, sc0);
    float so = __expf(m - mnew);
    float pe0 = __expf(sc0 - mnew);
    l = l * so + pe0;
    float vf0[8];
    unpack8(v0, vf0);
    for (int j = 0; j < 8; ++j) acc[j] = fmaf(acc[j], so, pe0 * vf0[j]);
    m = mnew;
  }

  float inv = 0.f;
  if (l > 0.f) inv = 1.0f / l;
  float val[8];
  for (int j = 0; j < 8; ++j) {
    float x = acc[j] * inv;
    x += __shfl_xor(x, 16);
    x += __shfl_xor(x, 32);
    val[j] = x * 0.25f;  // mean over 4 heads
  }

  if (head == 0) {
    float* p = out + (size_t)node * HID + r * 8;
    float4 a = *(const float4*)(p);
    float4 b = *(const float4*)(p + 4);
    a.x += val[0]; a.y += val[1]; a.z += val[2]; a.w += val[3];
    b.x += val[4]; b.y += val[5]; b.z += val[6]; b.w += val[7];
    *(float4*)(p) = a;
    *(float4*)(p + 4) = b;
  }
}

// ---------------- cvec = h_t @ Wup[128:256] + bup (all f32) ----------------
__global__ void cvec_kernel(const float* h_t, const float* Wup,
                            const float* bup, float* cvec) {
  int c = threadIdx.x;
  float acc = bup[c];
  for (int k = 0; k < 128; ++k)
    acc = fmaf(h_t[k], Wup[(size_t)(128 + k) * 128 + c], acc);
  cvec[c] = acc;
}

// ------- update GEMM + relu + LayerNorm, in-place on d_out (f32) -------
__global__ __launch_bounds__(256) void ATTLayer_19396072308956_kernel(
    float* out, const float* __restrict__ Wup, const float* __restrict__ cvec,
    const float* __restrict__ gamma, const float* __restrict__ beta, int N) {
  __shared__ float Wl[64 * 128];
  __shared__ float Hl[UT * 128];
  int t = threadIdx.x;
  int n0 = blockIdx.x * UT;

  for (int i = t * 4; i < UT * 128; i += 1024) {
    int node = n0 + (i >> 7);
    float4 v;
    if (node < N) {
      v = *(const float4*)(out + (size_t)node * HID + (i & 127));
    } else {
      v.x = 0.f; v.y = 0.f; v.z = 0.f; v.w = 0.f;
    }
    *(float4*)(Hl + i) = v;
  }

  int wv = t >> 6;
  int r = t & 63;
  int c0 = 2 * r;
  float2 cv = *(const float2*)(cvec + c0);
  float a0[8];
  float a1[8];
  for (int j = 0; j < 8; ++j) {
    a0[j] = cv.x;
    a1[j] = cv.y;
  }

  for (int ph = 0; ph < 2; ++ph) {
    __syncthreads();
    for (int i = t * 4; i < 64 * 128; i += 1024) {
      *(float4*)(Wl + i) = *(const float4*)(Wup + (size_t)ph * 64 * 128 + i);
    }
    __syncthreads();
    const float* hbase = Hl + (wv * 8) * 128 + ph * 64;
#pragma unroll 8
    for (int k = 0; k < 64; ++k) {
      float2 w2 = *(const float2*)(Wl + k * 128 + c0);
      for (int j = 0; j < 8; ++j) {
        float h = hbase[j * 128 + k];
        a0[j] = fmaf(h, w2.x, a0[j]);
        a1[j] = fmaf(h, w2.y, a1[j]);
      }
    }
  }

  float2 g = *(const float2*)(gamma + c0);
  float2 b = *(const float2*)(beta + c0);
  for (int j = 0; j < 8; ++j) {
    int node = n0 + wv * 8 + j;
    float r0 = fmaxf(a0[j], 0.f);
    float r1 = fmaxf(a1[j], 0.f);
    float s = r0 + r1;
    for (int msk = 1; msk < 64; msk <<= 1) s += __shfl_xor(s, msk);
    float mean = s * (1.0f / 128.0f);
    float d0 = r0 - mean;
    float d1 = r1 - mean;
    float sq = d0 * d0 + d1 * d1;
    for (int msk = 1; msk < 64; msk <<= 1) sq += __shfl_xor(sq, msk);
    float rstd = rsqrtf(sq * (1.0f / 128.0f) + 1e-5f);
    if (node < N) {
      float2 o;
      o.x = d0 * rstd * g.x + b.x;
      o.y = d1 * rstd * g.y + b.y;
      *(float2*)(out + (size_t)node * HID + c0) = o;
    }
  }
}

extern "C" void kernel_launch(void* const* d_in, const int* in_sizes, int n_in,
                              void* d_out, int out_size, void* d_ws,
                              size_t ws_size, hipStream_t stream) {
  (void)n_in;
  (void)out_size;
  (void)ws_size;

  const int* edge_index = (const int*)d_in[0];
  const float* hX    = (const float*)d_in[1];
  const float* h_t   = (const float*)d_in[2];
  const float* Wq    = (const float*)d_in[3];
  const float* bq    = (const float*)d_in[4];
  const float* Wk    = (const float*)d_in[5];
  const float* bk    = (const float*)d_in[6];
  const float* Wv    = (const float*)d_in[7];
  const float* bv    = (const float*)d_in[8];
  const float* Wskip = (const float*)d_in[9];
  const float* bskip = (const float*)d_in[10];
  const float* Wup   = (const float*)d_in[11];
  const float* bup   = (const float*)d_in[12];
  const float* gamma = (const float*)d_in[13];
  const float* beta  = (const float*)d_in[14];

  const int E = in_sizes[0] / 2;
  const int N = in_sizes[1] / HID;
  const int* src_idx = edge_index;
  const int* dst_idx = edge_index + E;
  const int NB = (N + 255) / 256;
  const int NTILES = (N + 15) / 16;
  const int NTILES4 = ((NTILES + 3) / 4) * 4;

  // ---- workspace layout (~170 MB peak, fits: proven round 12) ----
  char* w = (char*)d_ws;
  size_t off = 0;
  float* cvec = (float*)(w + off);
  off += 256 * 4;
  int* deg = (int*)(w + off);
  off += ((size_t)N * 4 + 255) / 256 * 256;
  int* row_ptr = (int*)(w + off);
  off += ((size_t)(N + 1) * 4 + 255) / 256 * 256;
  int* cursor = (int*)(w + off);
  off += ((size_t)N * 4 + 255) / 256 * 256;
  int* bsums = (int*)(w + off);
  off += ((size_t)NB * 4 + 255) / 256 * 256;
  int* boffs = (int*)(w + off);
  off += ((size_t)NB * 4 + 255) / 256 * 256;
  int* col = (int*)(w + off);
  off += ((size_t)E * 4 + 255) / 256 * 256;
  u16* hpack = (u16*)(w + off);
  off += ((size_t)NTILES4 * 2048 * 2 + 255) / 256 * 256;
  u16* Wp = (u16*)(w + off);     // [Wq|Wk|Wv|Wskip] 1664 cols, B-frag order
  off += ((size_t)128 * 1664 * 2 + 255) / 256 * 256;
  u16* bigA = (u16*)(w + off);   // q
  off += ((size_t)N * HC * 2 + 255) / 256 * 256;
  u16* bigB = (u16*)(w + off);   // k
  off += ((size_t)N * HC * 2 + 255) / 256 * 256;
  u16* bigC = (u16*)(w + off);   // v
  off += ((size_t)N * HC * 2 + 255) / 256 * 256;

  float* out = (float*)d_out;

  // ---- CSR build (parallel 3-phase scan) ----
  zero_kernel<<<NB, 256, 0, stream>>>(deg, N);
  hist_kernel<<<(E + 255) / 256, 256, 0, stream>>>(dst_idx, deg, E);
  blocksum_kernel<<<NB, 256, 0, stream>>>(deg, bsums, N);
  scanb_kernel<<<1, 256, 0, stream>>>(bsums, boffs, NB);
  scanfinal_kernel<<<NB, 256, 0, stream>>>(deg, boffs, row_ptr, cursor, N);
  scatter_kernel<<<(E + 255) / 256, 256, 0, stream>>>(src_idx, dst_idx, cursor,
                                                      col, E);

  // ---- packing for MFMA ----
  int totH = NTILES4 * 2048;
  packH_kernel<<<(totH + 255) / 256, 256, 0, stream>>>(hX, hpack, N, totH);
  packW4_kernel<<<(128 * 1664 + 255) / 256, 256, 0, stream>>>(
      Wq, Wk, Wv, Wskip, Wp, 128 * 1664);

  // ---- cvec ----
  cvec_kernel<<<1, 128, 0, stream>>>(h_t, Wup, bup, cvec);

  // ---- single MFMA projection: q->bigA, k->bigB, v->bigC, skip->d_out ----
  mfma_proj_kernel<<<dim3(NTILES4 / 4, 26), 256, 0, stream>>>(
      hpack, Wp, bq, bk, bv, bskip, bigA, bigB, bigC, out, N);

  // ---- fused score + online softmax + aggregate (4-edge unroll) ----
  fused_attn_kernel<<<(N + 3) / 4, 256, 0, stream>>>(bigA, bigB, bigC, row_ptr,
                                                     col, out, N);

  // ---- update GEMM + relu + LayerNorm, in-place on d_out (tiled) ----
  ATTLayer_19396072308956_kernel<<<(N + UT - 1) / UT, 256, 0, stream>>>(
      out, Wup, cvec, gamma, beta, N);
}